// Round 4
// baseline (6604.506 us; speedup 1.0000x reference)
//
#include <hip/hip_runtime.h>
#include <math.h>

// Point-MAE Group — FPS(2048) + kNN(16) + gather/subtract.
// B=4, N=16384, G=2048, M=16.
// Bit-replicates a mechanical numpy-f32 port of the jax reference:
//  - FPS: all ops separate (numpy materializes temps; no FMA anywhere).
//  - kNN: d2 = (cc - 2*dot) + xx, where ONLY dot uses an FMA chain
//    (numpy einsum's scalar accumulation loop contracts to fma under gcc):
//      dot = fma(c2,z, fma(c1,y, c0*x))
//    cc and xx are separate mul+add (materialized temps in numpy).
//  - FPS argmax: first occurrence of max; top-16: stable ascending order.

#pragma clang fp contract(off)

#define N_PTS 16384
#define N_GROUP 2048
#define GROUP_SIZE 16
#define FPS_THREADS 1024
#define PPT (N_PTS / FPS_THREADS)   // 16 points per thread
#define KNN_THREADS 256
#define KNN_WAVES (KNN_THREADS / 64)

// a*b as a standalone instruction the compiler cannot fuse into a later add.
__device__ __forceinline__ float fmul_sep(float a, float b) {
  float r = a * b;
  asm volatile("" : "+v"(r));
  return r;
}

// ---------------------------------------------------------------------------
// FPS: one block per batch. Points + min-dist chain in f32 registers.
// d = ((dx*dx)+(dy*dy))+(dz*dz), all separate ops; md = min(md, d);
// block argmax on (value, lowest index); winner coords ride the reduction.
// ---------------------------------------------------------------------------
__global__ __launch_bounds__(FPS_THREADS) void fps_kernel(
    const float* __restrict__ pcd, float* __restrict__ center) {
#pragma clang fp contract(off)
  const int b = blockIdx.x;
  const int t = threadIdx.x;
  const int lane = t & 63;
  const int wid = t >> 6;
  const float* xyz = pcd + (size_t)b * N_PTS * 3;

  float x[PPT], y[PPT], z[PPT], md[PPT];
#pragma unroll
  for (int i = 0; i < PPT; ++i) {
    const int idx = t * PPT + i;
    x[i] = xyz[idx * 3 + 0];
    y[i] = xyz[idx * 3 + 1];
    z[i] = xyz[idx * 3 + 2];
    md[i] = 1e10f;
  }

  float px = xyz[0], py = xyz[1], pz = xyz[2];
  if (t == 0) {
    center[((size_t)b * N_GROUP) * 3 + 0] = px;
    center[((size_t)b * N_GROUP) * 3 + 1] = py;
    center[((size_t)b * N_GROUP) * 3 + 2] = pz;
  }

  __shared__ float sv[16], sx[16], sy[16], sz[16];
  __shared__ int si[16];

  for (int it = 1; it < N_GROUP; ++it) {
    float bv = -1.0f;
    int bi = 0;
    float bx = 0.f, by = 0.f, bz = 0.f;
#pragma unroll
    for (int i = 0; i < PPT; ++i) {
      const float dx = x[i] - px;
      const float dy = y[i] - py;
      const float dz = z[i] - pz;
      const float d = (fmul_sep(dx, dx) + fmul_sep(dy, dy)) + fmul_sep(dz, dz);
      const float m = fminf(md[i], d);
      md[i] = m;
      if (m > bv) {  // strict >: lowest index wins ties (np.argmax)
        bv = m; bi = t * PPT + i; bx = x[i]; by = y[i]; bz = z[i];
      }
    }
#pragma unroll
    for (int off = 32; off > 0; off >>= 1) {
      const float ov = __shfl_xor(bv, off);
      const int   oi = __shfl_xor(bi, off);
      const float ox = __shfl_xor(bx, off);
      const float oy = __shfl_xor(by, off);
      const float oz = __shfl_xor(bz, off);
      if (ov > bv || (ov == bv && oi < bi)) {
        bv = ov; bi = oi; bx = ox; by = oy; bz = oz;
      }
    }
    if (lane == 0) {
      sv[wid] = bv; si[wid] = bi; sx[wid] = bx; sy[wid] = by; sz[wid] = bz;
    }
    __syncthreads();
    {
      const int l = lane & 15;
      bv = sv[l]; bi = si[l]; bx = sx[l]; by = sy[l]; bz = sz[l];
#pragma unroll
      for (int off = 8; off > 0; off >>= 1) {
        const float ov = __shfl_xor(bv, off);
        const int   oi = __shfl_xor(bi, off);
        const float ox = __shfl_xor(bx, off);
        const float oy = __shfl_xor(by, off);
        const float oz = __shfl_xor(bz, off);
        if (ov > bv || (ov == bv && oi < bi)) {
          bv = ov; bi = oi; bx = ox; by = oy; bz = oz;
        }
      }
    }
    px = bx; py = by; pz = bz;  // identical in all threads
    if (t == 0) {
      center[((size_t)b * N_GROUP + it) * 3 + 0] = bx;
      center[((size_t)b * N_GROUP + it) * 3 + 1] = by;
      center[((size_t)b * N_GROUP + it) * 3 + 2] = bz;
    }
    __syncthreads();
  }
}

// ---------------------------------------------------------------------------
// kNN: one wave per center; lanes 0..15 hold the sorted top-16.
// d2 = (cc - 2*dot) + xx; cc/xx separate ops; dot = FMA chain (einsum).
// ---------------------------------------------------------------------------
__global__ __launch_bounds__(KNN_THREADS) void knn_kernel(
    const float* __restrict__ pcd, const float* __restrict__ center,
    float* __restrict__ nbr) {
#pragma clang fp contract(off)
  const int lane = threadIdx.x & 63;
  const int gw = blockIdx.x * KNN_WAVES + (threadIdx.x >> 6);  // center id
  const int b = gw >> 11;                                      // G = 2048
  const float* xyz = pcd + (size_t)b * N_PTS * 3;

  const float c0 = center[(size_t)gw * 3 + 0];
  const float c1 = center[(size_t)gw * 3 + 1];
  const float c2 = center[(size_t)gw * 3 + 2];
  const float cc = (fmul_sep(c0, c0) + fmul_sep(c1, c1)) + fmul_sep(c2, c2);

  float lval = INFINITY;  // lanes 0..15: sorted list values (ascending)
  int lidx = 0;
  float worst = INFINITY; // 16th-smallest so far, wave-uniform

  for (int ch = 0; ch < N_PTS / 64; ++ch) {
    const int n = ch * 64 + lane;
    const float xp = xyz[n * 3 + 0];
    const float yp = xyz[n * 3 + 1];
    const float zp = xyz[n * 3 + 2];
    const float xx = (fmul_sep(xp, xp) + fmul_sep(yp, yp)) + fmul_sep(zp, zp);
    // numpy einsum: acc=0; acc=fma(c0,x,acc); acc=fma(c1,y,acc); acc=fma(c2,z,acc)
    const float dot = fmaf(c2, zp, fmaf(c1, yp, c0 * xp));
    const float d2 = (cc - fmul_sep(2.0f, dot)) + xx;

    unsigned long long m = __ballot(d2 < worst);
    while (m) {
      const int srcl = __ffsll((unsigned long long)m) - 1;  // ascending index
      m &= (m - 1);
      const float nv = __shfl(d2, srcl);
      if (nv < worst) {  // wave-uniform decision
        const int ni = ch * 64 + srcl;
        const int rank = __popcll(__ballot(lane < GROUP_SIZE && lval <= nv));
        const float shv = __shfl_up(lval, 1);
        const int   shi = __shfl_up(lidx, 1);
        if (lane < GROUP_SIZE) {
          if (lane == rank)      { lval = nv;  lidx = ni;  }
          else if (lane > rank)  { lval = shv; lidx = shi; }
        }
        worst = __shfl(lval, 15);
      }
    }
  }

  if (lane < GROUP_SIZE) {
    const float ox = xyz[lidx * 3 + 0] - c0;
    const float oy = xyz[lidx * 3 + 1] - c1;
    const float oz = xyz[lidx * 3 + 2] - c2;
    const size_t o = ((size_t)gw * GROUP_SIZE + lane) * 3;
    nbr[o + 0] = ox; nbr[o + 1] = oy; nbr[o + 2] = oz;
  }
}

extern "C" void kernel_launch(void* const* d_in, const int* in_sizes, int n_in,
                              void* d_out, int out_size, void* d_ws, size_t ws_size,
                              hipStream_t stream) {
  const float* pcd = (const float*)d_in[0];
  const int B = in_sizes[0] / (N_PTS * 3);  // = 4

  float* out = (float*)d_out;
  float* nbr = out;                                            // B*G*M*3
  float* center = out + (size_t)B * N_GROUP * GROUP_SIZE * 3;  // B*G*3

  fps_kernel<<<B, FPS_THREADS, 0, stream>>>(pcd, center);
  knn_kernel<<<(B * N_GROUP) / KNN_WAVES, KNN_THREADS, 0, stream>>>(pcd, center, nbr);
}

// Round 5
// 4726.771 us; speedup vs baseline: 1.3973x; 1.3973x over previous
//
#include <hip/hip_runtime.h>
#include <math.h>

// Point-MAE Group — FPS(2048) + kNN(16) + gather/subtract.
// B=4, N=16384, G=2048, M=16.
// Bit-replicates a mechanical numpy-f32 port of the jax reference (verified
// absmax=0.0 in round 4):
//  - FPS: all ops separate (numpy materializes temps; no FMA anywhere).
//  - kNN: d2 = (cc - 2*dot) + xx, ONLY dot is an FMA chain (numpy einsum).
//  - FPS argmax: first occurrence of max; top-16: stable ascending order.
// DO NOT change per-point arithmetic — the selection decisions depend on it.
//
// Round-5 perf changes (selection-identical by construction):
//  - fps: 512 threads (8 waves), PPT=32.
//  - packed u64 key = (float_bits(v)<<32)|(16383-idx): u64 order == lexicographic
//    (value, lowest-index) order for the non-negative md values.
//  - wave reduce carries key + coords (coords are bit-copies, never recomputed).
//  - cross-wave stage: sequential scan of 8 LDS entries (broadcast reads).
//  - double-buffered LDS result slots -> single __syncthreads per iteration.

#pragma clang fp contract(off)

#define N_PTS 16384
#define N_GROUP 2048
#define GROUP_SIZE 16
#define FPS_THREADS 512
#define PPT (N_PTS / FPS_THREADS)   // 32 points per thread
#define FPS_WAVES (FPS_THREADS / 64)
#define KNN_THREADS 256
#define KNN_WAVES (KNN_THREADS / 64)

// a*b as a standalone instruction the compiler cannot fuse into a later add.
__device__ __forceinline__ float fmul_sep(float a, float b) {
  float r = a * b;
  asm volatile("" : "+v"(r));
  return r;
}

__device__ __forceinline__ unsigned long long shfl_xor_u64(unsigned long long v, int off) {
  const unsigned int lo = __shfl_xor((unsigned int)v, off);
  const unsigned int hi = __shfl_xor((unsigned int)(v >> 32), off);
  return ((unsigned long long)hi << 32) | lo;
}

// ---------------------------------------------------------------------------
// FPS: one block per batch. Points + min-dist chain in f32 registers.
// d = ((dx*dx)+(dy*dy))+(dz*dz), all separate ops; md = min(md, d);
// block argmax on (value, lowest index) via packed u64 keys.
// ---------------------------------------------------------------------------
__global__ __launch_bounds__(FPS_THREADS, 2) void fps_kernel(
    const float* __restrict__ pcd, float* __restrict__ center) {
#pragma clang fp contract(off)
  const int b = blockIdx.x;
  const int t = threadIdx.x;
  const int lane = t & 63;
  const int wid = t >> 6;
  const float* xyz = pcd + (size_t)b * N_PTS * 3;
  const int base = t * PPT;

  float x[PPT], y[PPT], z[PPT], md[PPT];
#pragma unroll
  for (int i = 0; i < PPT; ++i) {
    const int idx = base + i;
    x[i] = xyz[idx * 3 + 0];
    y[i] = xyz[idx * 3 + 1];
    z[i] = xyz[idx * 3 + 2];
    md[i] = 1e10f;
  }

  float px = xyz[0], py = xyz[1], pz = xyz[2];
  if (t == 0) {
    center[((size_t)b * N_GROUP) * 3 + 0] = px;
    center[((size_t)b * N_GROUP) * 3 + 1] = py;
    center[((size_t)b * N_GROUP) * 3 + 2] = pz;
  }

  // double-buffered per-wave results: key + winner coords
  __shared__ unsigned long long skey[2][FPS_WAVES];
  __shared__ float sx[2][FPS_WAVES], sy[2][FPS_WAVES], sz[2][FPS_WAVES];

  for (int it = 1; it < N_GROUP; ++it) {
    const int p = it & 1;
    float bv = -1.0f;
    int bi = 0;
    float bx = 0.f, by = 0.f, bz = 0.f;
#pragma unroll
    for (int i = 0; i < PPT; ++i) {
      const float dx = x[i] - px;
      const float dy = y[i] - py;
      const float dz = z[i] - pz;
      const float d = (fmul_sep(dx, dx) + fmul_sep(dy, dy)) + fmul_sep(dz, dz);
      const float m = fminf(md[i], d);
      md[i] = m;
      if (m > bv) {  // strict >: lowest index wins ties (np.argmax)
        bv = m; bi = base + i; bx = x[i]; by = y[i]; bz = z[i];
      }
    }
    // bv >= 0 here (squared distances), so IEEE bit order == value order.
    unsigned long long key =
        ((unsigned long long)__float_as_uint(bv) << 32) |
        (unsigned int)(N_PTS - 1 - bi);  // higher low-word = lower index

    // wave reduce: max key; winner coords ride along (bit-copies).
#pragma unroll
    for (int off = 32; off > 0; off >>= 1) {
      const unsigned long long ok = shfl_xor_u64(key, off);
      const float ox = __shfl_xor(bx, off);
      const float oy = __shfl_xor(by, off);
      const float oz = __shfl_xor(bz, off);
      if (ok > key) { key = ok; bx = ox; by = oy; bz = oz; }
    }
    if (lane == 0) {
      skey[p][wid] = key; sx[p][wid] = bx; sy[p][wid] = by; sz[p][wid] = bz;
    }
    __syncthreads();
    // cross-wave: sequential scan of FPS_WAVES entries (broadcast LDS reads).
    unsigned long long bk = skey[p][0];
    int bj = 0;
#pragma unroll
    for (int j = 1; j < FPS_WAVES; ++j) {
      const unsigned long long kj = skey[p][j];
      if (kj > bk) { bk = kj; bj = j; }
    }
    px = sx[p][bj]; py = sy[p][bj]; pz = sz[p][bj];
    if (t == 0) {
      center[((size_t)b * N_GROUP + it) * 3 + 0] = px;
      center[((size_t)b * N_GROUP + it) * 3 + 1] = py;
      center[((size_t)b * N_GROUP + it) * 3 + 2] = pz;
    }
    // no second barrier: next iteration writes the other LDS slot, and the
    // (it+2) reuse of this slot is fenced by the (it+1) barrier.
  }
}

// ---------------------------------------------------------------------------
// kNN: one wave per center; lanes 0..15 hold the sorted top-16.
// d2 = (cc - 2*dot) + xx; cc/xx separate ops; dot = FMA chain (einsum).
// (unchanged from the bit-exact round-4 version)
// ---------------------------------------------------------------------------
__global__ __launch_bounds__(KNN_THREADS) void knn_kernel(
    const float* __restrict__ pcd, const float* __restrict__ center,
    float* __restrict__ nbr) {
#pragma clang fp contract(off)
  const int lane = threadIdx.x & 63;
  const int gw = blockIdx.x * KNN_WAVES + (threadIdx.x >> 6);  // center id
  const int b = gw >> 11;                                      // G = 2048
  const float* xyz = pcd + (size_t)b * N_PTS * 3;

  const float c0 = center[(size_t)gw * 3 + 0];
  const float c1 = center[(size_t)gw * 3 + 1];
  const float c2 = center[(size_t)gw * 3 + 2];
  const float cc = (fmul_sep(c0, c0) + fmul_sep(c1, c1)) + fmul_sep(c2, c2);

  float lval = INFINITY;  // lanes 0..15: sorted list values (ascending)
  int lidx = 0;
  float worst = INFINITY; // 16th-smallest so far, wave-uniform

  for (int ch = 0; ch < N_PTS / 64; ++ch) {
    const int n = ch * 64 + lane;
    const float xp = xyz[n * 3 + 0];
    const float yp = xyz[n * 3 + 1];
    const float zp = xyz[n * 3 + 2];
    const float xx = (fmul_sep(xp, xp) + fmul_sep(yp, yp)) + fmul_sep(zp, zp);
    // numpy einsum: acc=0; acc=fma(c0,x,acc); acc=fma(c1,y,acc); acc=fma(c2,z,acc)
    const float dot = fmaf(c2, zp, fmaf(c1, yp, c0 * xp));
    const float d2 = (cc - fmul_sep(2.0f, dot)) + xx;

    unsigned long long m = __ballot(d2 < worst);
    while (m) {
      const int srcl = __ffsll((unsigned long long)m) - 1;  // ascending index
      m &= (m - 1);
      const float nv = __shfl(d2, srcl);
      if (nv < worst) {  // wave-uniform decision
        const int ni = ch * 64 + srcl;
        const int rank = __popcll(__ballot(lane < GROUP_SIZE && lval <= nv));
        const float shv = __shfl_up(lval, 1);
        const int   shi = __shfl_up(lidx, 1);
        if (lane < GROUP_SIZE) {
          if (lane == rank)      { lval = nv;  lidx = ni;  }
          else if (lane > rank)  { lval = shv; lidx = shi; }
        }
        worst = __shfl(lval, 15);
      }
    }
  }

  if (lane < GROUP_SIZE) {
    const float ox = xyz[lidx * 3 + 0] - c0;
    const float oy = xyz[lidx * 3 + 1] - c1;
    const float oz = xyz[lidx * 3 + 2] - c2;
    const size_t o = ((size_t)gw * GROUP_SIZE + lane) * 3;
    nbr[o + 0] = ox; nbr[o + 1] = oy; nbr[o + 2] = oz;
  }
}

extern "C" void kernel_launch(void* const* d_in, const int* in_sizes, int n_in,
                              void* d_out, int out_size, void* d_ws, size_t ws_size,
                              hipStream_t stream) {
  const float* pcd = (const float*)d_in[0];
  const int B = in_sizes[0] / (N_PTS * 3);  // = 4

  float* out = (float*)d_out;
  float* nbr = out;                                            // B*G*M*3
  float* center = out + (size_t)B * N_GROUP * GROUP_SIZE * 3;  // B*G*3

  fps_kernel<<<B, FPS_THREADS, 0, stream>>>(pcd, center);
  knn_kernel<<<(B * N_GROUP) / KNN_WAVES, KNN_THREADS, 0, stream>>>(pcd, center, nbr);
}

// Round 6
// 3944.299 us; speedup vs baseline: 1.6744x; 1.1984x over previous
//
#include <hip/hip_runtime.h>
#include <math.h>

// Point-MAE Group — FPS(2048) + kNN(16) + gather/subtract.
// B=4, N=16384, G=2048, M=16.
// NUMERICS CONTRACT (verified absmax=0.0 in rounds 4/5 — do not change):
//  - FPS: d = ((dx*dx)+(dy*dy))+(dz*dz), all separate f32 ops, no FMA.
//    (#pragma clang fp contract(off) alone is sufficient — proven r1==r3.)
//  - kNN: d2 = (cc - 2*dot) + xx; ONLY dot is an FMA chain (numpy einsum).
//  - FPS argmax: first occurrence of max; top-16: stable ascending order.
//
// Round-6 perf changes (selection-identical by construction):
//  - FPS: removed asm mul-barriers (pragma suffices) -> scheduler/regalloc
//    freedom so x/y/z/md (128 VGPRs) stay register-resident (was: rematerialized
//    global reloads every iteration, FETCH 406KB, VGPR=88).
//  - per-point argmax tracks (value, local idx) only: 12 VALU/point.
//  - winner coords: after key-only wave reduce, lane 0 loads the candidate's
//    12B from pcd (bit-copies) into LDS pre-barrier; latency hides under the
//    barrier. No coord shuffles, no per-point coord cndmasks.

#pragma clang fp contract(off)

#define N_PTS 16384
#define N_GROUP 2048
#define GROUP_SIZE 16
#define FPS_THREADS 512
#define PPT (N_PTS / FPS_THREADS)   // 32 points per thread
#define FPS_WAVES (FPS_THREADS / 64)
#define KNN_THREADS 256
#define KNN_WAVES (KNN_THREADS / 64)

// a*b as a standalone instruction (kNN only — keep the exact passing form).
__device__ __forceinline__ float fmul_sep(float a, float b) {
  float r = a * b;
  asm volatile("" : "+v"(r));
  return r;
}

__device__ __forceinline__ unsigned long long shfl_xor_u64(unsigned long long v, int off) {
  const unsigned int lo = __shfl_xor((unsigned int)v, off);
  const unsigned int hi = __shfl_xor((unsigned int)(v >> 32), off);
  return ((unsigned long long)hi << 32) | lo;
}

// ---------------------------------------------------------------------------
// FPS: one block per batch. Points + min-dist chain in f32 registers.
// Block argmax on (value, lowest index) via packed u64 keys.
// ---------------------------------------------------------------------------
__global__ __launch_bounds__(FPS_THREADS, 2) void fps_kernel(
    const float* __restrict__ pcd, float* __restrict__ center) {
#pragma clang fp contract(off)
  const int b = blockIdx.x;
  const int t = threadIdx.x;
  const int lane = t & 63;
  const int wid = t >> 6;
  const float* xyz = pcd + (size_t)b * N_PTS * 3;
  const int base = t * PPT;

  float x[PPT], y[PPT], z[PPT], md[PPT];
#pragma unroll
  for (int i = 0; i < PPT; ++i) {
    const int idx = base + i;
    x[i] = xyz[idx * 3 + 0];
    y[i] = xyz[idx * 3 + 1];
    z[i] = xyz[idx * 3 + 2];
    md[i] = 1e10f;
  }

  float px = xyz[0], py = xyz[1], pz = xyz[2];
  if (t == 0) {
    center[((size_t)b * N_GROUP) * 3 + 0] = px;
    center[((size_t)b * N_GROUP) * 3 + 1] = py;
    center[((size_t)b * N_GROUP) * 3 + 2] = pz;
  }

  // double-buffered per-wave results: key + candidate coords
  __shared__ unsigned long long skey[2][FPS_WAVES];
  __shared__ float sx[2][FPS_WAVES], sy[2][FPS_WAVES], sz[2][FPS_WAVES];

  for (int it = 1; it < N_GROUP; ++it) {
    const int p = it & 1;
    float bv = -1.0f;
    int ii = 0;  // local point index of current best (0..31)
#pragma unroll
    for (int i = 0; i < PPT; ++i) {
      const float dx = x[i] - px;
      const float dy = y[i] - py;
      const float dz = z[i] - pz;
      const float d = ((dx * dx) + (dy * dy)) + (dz * dz);  // no-FMA via pragma
      const float m = fminf(md[i], d);
      md[i] = m;
      if (m > bv) { bv = m; ii = i; }  // strict >: lowest index wins ties
    }
    const int bi = base + ii;
    // bv >= 0 (squared distance), so IEEE bit order == value order.
    unsigned long long key =
        ((unsigned long long)__float_as_uint(bv) << 32) |
        (unsigned int)(N_PTS - 1 - bi);  // higher low-word = lower index

    // wave reduce: max key (value, then lowest index)
#pragma unroll
    for (int off = 32; off > 0; off >>= 1) {
      const unsigned long long ok = shfl_xor_u64(key, off);
      if (ok > key) key = ok;
    }
    if (lane == 0) {
      // wave-winner coords: bit-copies straight from memory, hidden by barrier
      const int kidx = N_PTS - 1 - (int)(unsigned int)(key & 0xffffffffu);
      skey[p][wid] = key;
      sx[p][wid] = xyz[kidx * 3 + 0];
      sy[p][wid] = xyz[kidx * 3 + 1];
      sz[p][wid] = xyz[kidx * 3 + 2];
    }
    __syncthreads();
    // cross-wave: sequential scan of FPS_WAVES keys (broadcast LDS reads)
    unsigned long long bk = skey[p][0];
    int bj = 0;
#pragma unroll
    for (int j = 1; j < FPS_WAVES; ++j) {
      const unsigned long long kj = skey[p][j];
      if (kj > bk) { bk = kj; bj = j; }
    }
    px = sx[p][bj]; py = sy[p][bj]; pz = sz[p][bj];
    if (t == 0) {
      center[((size_t)b * N_GROUP + it) * 3 + 0] = px;
      center[((size_t)b * N_GROUP + it) * 3 + 1] = py;
      center[((size_t)b * N_GROUP + it) * 3 + 2] = pz;
    }
    // single barrier/iter: next iter writes the other slot; slot reuse at
    // it+2 is fenced by the it+1 barrier.
  }
}

// ---------------------------------------------------------------------------
// kNN: one wave per center; lanes 0..15 hold the sorted top-16.
// d2 = (cc - 2*dot) + xx; cc/xx separate ops; dot = FMA chain (einsum).
// (unchanged from the bit-exact round-4 version)
// ---------------------------------------------------------------------------
__global__ __launch_bounds__(KNN_THREADS) void knn_kernel(
    const float* __restrict__ pcd, const float* __restrict__ center,
    float* __restrict__ nbr) {
#pragma clang fp contract(off)
  const int lane = threadIdx.x & 63;
  const int gw = blockIdx.x * KNN_WAVES + (threadIdx.x >> 6);  // center id
  const int b = gw >> 11;                                      // G = 2048
  const float* xyz = pcd + (size_t)b * N_PTS * 3;

  const float c0 = center[(size_t)gw * 3 + 0];
  const float c1 = center[(size_t)gw * 3 + 1];
  const float c2 = center[(size_t)gw * 3 + 2];
  const float cc = (fmul_sep(c0, c0) + fmul_sep(c1, c1)) + fmul_sep(c2, c2);

  float lval = INFINITY;  // lanes 0..15: sorted list values (ascending)
  int lidx = 0;
  float worst = INFINITY; // 16th-smallest so far, wave-uniform

  for (int ch = 0; ch < N_PTS / 64; ++ch) {
    const int n = ch * 64 + lane;
    const float xp = xyz[n * 3 + 0];
    const float yp = xyz[n * 3 + 1];
    const float zp = xyz[n * 3 + 2];
    const float xx = (fmul_sep(xp, xp) + fmul_sep(yp, yp)) + fmul_sep(zp, zp);
    // numpy einsum: acc=0; acc=fma(c0,x,acc); acc=fma(c1,y,acc); acc=fma(c2,z,acc)
    const float dot = fmaf(c2, zp, fmaf(c1, yp, c0 * xp));
    const float d2 = (cc - fmul_sep(2.0f, dot)) + xx;

    unsigned long long m = __ballot(d2 < worst);
    while (m) {
      const int srcl = __ffsll((unsigned long long)m) - 1;  // ascending index
      m &= (m - 1);
      const float nv = __shfl(d2, srcl);
      if (nv < worst) {  // wave-uniform decision
        const int ni = ch * 64 + srcl;
        const int rank = __popcll(__ballot(lane < GROUP_SIZE && lval <= nv));
        const float shv = __shfl_up(lval, 1);
        const int   shi = __shfl_up(lidx, 1);
        if (lane < GROUP_SIZE) {
          if (lane == rank)      { lval = nv;  lidx = ni;  }
          else if (lane > rank)  { lval = shv; lidx = shi; }
        }
        worst = __shfl(lval, 15);
      }
    }
  }

  if (lane < GROUP_SIZE) {
    const float ox = xyz[lidx * 3 + 0] - c0;
    const float oy = xyz[lidx * 3 + 1] - c1;
    const float oz = xyz[lidx * 3 + 2] - c2;
    const size_t o = ((size_t)gw * GROUP_SIZE + lane) * 3;
    nbr[o + 0] = ox; nbr[o + 1] = oy; nbr[o + 2] = oz;
  }
}

extern "C" void kernel_launch(void* const* d_in, const int* in_sizes, int n_in,
                              void* d_out, int out_size, void* d_ws, size_t ws_size,
                              hipStream_t stream) {
  const float* pcd = (const float*)d_in[0];
  const int B = in_sizes[0] / (N_PTS * 3);  // = 4

  float* out = (float*)d_out;
  float* nbr = out;                                            // B*G*M*3
  float* center = out + (size_t)B * N_GROUP * GROUP_SIZE * 3;  // B*G*3

  fps_kernel<<<B, FPS_THREADS, 0, stream>>>(pcd, center);
  knn_kernel<<<(B * N_GROUP) / KNN_WAVES, KNN_THREADS, 0, stream>>>(pcd, center, nbr);
}